// Round 11
// baseline (238.342 us; speedup 1.0000x reference)
//
#include <hip/hip_runtime.h>
#include <hip/hip_bf16.h>
#include <stdint.h>

// ConstrastiveLoss2: loss = (sum_i lse_row(i) + sum_j lse_col(j) - 2*tau*sum_e a[e]b[e]) / (2B)
// logits = tau * ftir @ raman^T, tau = min(exp(log_tau), 100), B=4096, D=512.
// R11: revert R10 (sync fp32 staging = 60us gemm). Fuse cast INTO the gemm
// dispatch via producer/consumer: per-XCD work-stealing cast queues (panel-
// contiguous shares) -> per-panel ready counters -> gemm blocks spin+acquire,
// then run R9's verified 3-stage vmcnt-pipelined bf16 gemm unchanged.

typedef float f32x4 __attribute__((ext_vector_type(4)));
typedef __bf16 bf16x8 __attribute__((ext_vector_type(8)));
typedef __bf16 bf16x4 __attribute__((ext_vector_type(4)));

#define B_DIM 4096
#define D_DIM 512
#define NCHUNK 32   // partial chunks per row/col (one per 128-tile in the other dim)

__device__ __forceinline__ void gld_lds16(const void* g, void* l) {
  __builtin_amdgcn_global_load_lds(
      (const __attribute__((address_space(1))) unsigned int*)g,
      (__attribute__((address_space(3))) unsigned int*)l,
      16, 0, 0);
}

// ---------------- fused cast + GEMM + lse-partials kernel ----------------
// 1024 blocks (XCD-swizzled). Phase 1: drain this XCD's cast queue (64 shares
// of 8 rows each: fp32->bf16 swizzled panels + diag partials). Phase 2: wait
// for own panels, then BK=32 3-stage pipelined MFMA gemm (R9-identical).
__global__ __launch_bounds__(256, 3) void fused_kernel(
    const float* __restrict__ Af, const float* __restrict__ Bf,
    const float* __restrict__ log_tau,
    __bf16* __restrict__ Abf, __bf16* __restrict__ Bbf,
    float* __restrict__ diagp,
    unsigned* __restrict__ qcnt,   // [8]  per-XCD share queues
    unsigned* __restrict__ pcnt,   // [32] per-panel completion counters (16 shares each)
    float* __restrict__ row_pmax, float* __restrict__ row_psum,
    float* __restrict__ col_pmax, float* __restrict__ col_psum) {
  __shared__ char smem[49152];                 // gemm: 3 stages x 16KB; cast/epilogue overlay
  const int blk = blockIdx.x;
  const int xcd = blk & 7, loc = blk >> 3;
  const int bm = (xcd & 3) * 8 + (loc & 7);
  const int bn = (xcd >> 2) * 16 + (loc >> 3);
  const int t = threadIdx.x;
  const int lane = t & 63;
  const int w = t >> 6;

  // ================= Phase 1: work-stealing cast =================
  volatile int* sh_i = (volatile int*)smem;
  volatile float* sh_f = (volatile float*)(smem + 64);
  const float4* A4 = (const float4*)Af;
  const float4* B4 = (const float4*)Bf;
  bf16x4* Ab4 = (bf16x4*)Abf;
  bf16x4* Bb4 = (bf16x4*)Bbf;
  for (;;) {
    __syncthreads();
    if (t == 0) sh_i[0] = (int)atomicAdd(&qcnt[xcd], 1u);
    __syncthreads();
    int sl = sh_i[0];
    if (sl >= 64) break;                       // uniform: queue drained
    int s = xcd * 64 + sl;                     // share: rows [8s, 8s+8) of A and B
    float local = 0.f;
    #pragma unroll
    for (int it = 0; it < 4; ++it) {
      int idx = s * 1024 + it * 256 + t;       // float4 index
      int row = idx >> 7, el4 = idx & 127;     // el4: [2:1]=16B-block g, [0]=8B half
      int g = (el4 >> 1) & 3;
      int gswz = g ^ ((row >> 1) & 3);
      int el4p = (el4 & ~6) | (gswz << 1);
      int pidx = row * 128 + el4p;
      float4 va = A4[idx], vb = B4[idx];
      bf16x4 oa, ob;
      oa[0]=(__bf16)va.x; oa[1]=(__bf16)va.y; oa[2]=(__bf16)va.z; oa[3]=(__bf16)va.w;
      ob[0]=(__bf16)vb.x; ob[1]=(__bf16)vb.y; ob[2]=(__bf16)vb.z; ob[3]=(__bf16)vb.w;
      Ab4[pidx] = oa; Bb4[pidx] = ob;
      local += va.x*vb.x + va.y*vb.y + va.z*vb.z + va.w*vb.w;
    }
    #pragma unroll
    for (int off = 1; off < 64; off <<= 1) local += __shfl_xor(local, off);
    if (lane == 0) sh_f[w] = local;
    __syncthreads();                           // also drains all panel stores to L2
    if (t == 0) {
      diagp[s] = sh_f[0] + sh_f[1] + sh_f[2] + sh_f[3];
      __threadfence();                         // release: writeback XCD L2
      atomicAdd(&pcnt[s >> 4], 1u);            // panel = s>>4 (16 shares/panel)
    }
  }

  // ================= Phase 2: wait for this tile's panels =================
  if (t == 0) {
    while (__hip_atomic_load(&pcnt[bm], __ATOMIC_RELAXED, __HIP_MEMORY_SCOPE_AGENT) < 16u)
      __builtin_amdgcn_s_sleep(16);
    while (__hip_atomic_load(&pcnt[bn], __ATOMIC_RELAXED, __HIP_MEMORY_SCOPE_AGENT) < 16u)
      __builtin_amdgcn_s_sleep(16);
  }
  __syncthreads();
  __threadfence();                             // acquire: invalidate stale cache lines

  // ================= Phase 3: R9 gemm (verified) =================
  const int wm = (w >> 1) * 64, wn = (w & 1) * 64;
  const int q = lane >> 4, c16 = lane & 15;
  const int kbs = q ^ ((c16 >> 1) & 3);        // physical 16B-block for this lane

  f32x4 acc[4][4] = {};

  const char* Ag = (const char*)Abf + (size_t)(bm * 128 + (t >> 2)) * 1024 + (t & 3) * 16;
  const char* Bg = (const char*)Bbf + (size_t)(bn * 128 + (t >> 2)) * 1024 + (t & 3) * 16;

  #define ISSUE_STAGE(kt, p)                                                  \
    do {                                                                      \
      const char* ag = Ag + (kt) * 64;                                        \
      const char* bg = Bg + (kt) * 64;                                        \
      char* Al = smem + (p) * 16384 + t * 16;                                 \
      char* Bl = smem + (p) * 16384 + 8192 + t * 16;                          \
      _Pragma("unroll")                                                       \
      for (int i = 0; i < 2; ++i) {                                           \
        gld_lds16(ag + i * 65536, Al + i * 4096);                             \
        gld_lds16(bg + i * 65536, Bl + i * 4096);                             \
      }                                                                       \
    } while (0)

  #define COMPUTE(p)                                                          \
    do {                                                                      \
      const char* Ab = smem + (p) * 16384;                                    \
      const char* Bb = Ab + 8192;                                             \
      bf16x8 af[4], bfr[4];                                                   \
      _Pragma("unroll")                                                       \
      for (int mi = 0; mi < 4; ++mi)                                          \
        af[mi] = *(const bf16x8*)(Ab + (wm + mi * 16 + c16) * 64 + kbs * 16); \
      _Pragma("unroll")                                                       \
      for (int ni = 0; ni < 4; ++ni)                                          \
        bfr[ni] = *(const bf16x8*)(Bb + (wn + ni * 16 + c16) * 64 + kbs * 16);\
      _Pragma("unroll")                                                       \
      for (int mi = 0; mi < 4; ++mi)                                          \
        _Pragma("unroll")                                                     \
        for (int ni = 0; ni < 4; ++ni)                                        \
          acc[mi][ni] = __builtin_amdgcn_mfma_f32_16x16x32_bf16(              \
              af[mi], bfr[ni], acc[mi][ni], 0, 0, 0);                         \
    } while (0)

  __syncthreads();                             // smem free (cast overlay done)
  ISSUE_STAGE(0, 0);
  ISSUE_STAGE(1, 1);
  for (int kt = 0; kt < 15; ++kt) {
    asm volatile("s_waitcnt vmcnt(4)" ::: "memory");  // stage kt landed; kt+1 in flight
    __builtin_amdgcn_s_barrier();              // raw: no full drain
    asm volatile("" ::: "memory");
    if (kt < 14) ISSUE_STAGE(kt + 2, (kt + 2) % 3);   // buf (kt-1)%3: readers done
    COMPUTE(kt % 3);
  }
  asm volatile("s_waitcnt vmcnt(0)" ::: "memory");
  __builtin_amdgcn_s_barrier();
  asm volatile("" ::: "memory");
  COMPUTE(15 % 3);
  __syncthreads();                             // all reads done before epilogue overlay
  #undef ISSUE_STAGE
  #undef COMPUTE

  const float tau = fminf(__expf(log_tau[0]), 100.0f);
  #pragma unroll
  for (int mi = 0; mi < 4; ++mi)
    #pragma unroll
    for (int ni = 0; ni < 4; ++ni)
      acc[mi][ni] *= tau;

  // C layout (m89): col = wn + ni*16 + c16, row = wm + mi*16 + q*4 + r.
  // ---- rows phase 1: per-lane reduce over 4 ni values, scatter to rowbuf[128][33] ----
  float2* rbuf = (float2*)smem;
  #pragma unroll
  for (int mi = 0; mi < 4; ++mi)
    #pragma unroll
    for (int r = 0; r < 4; ++r) {
      float v0 = acc[mi][0][r], v1 = acc[mi][1][r], v2 = acc[mi][2][r], v3 = acc[mi][3][r];
      float m = fmaxf(fmaxf(v0, v1), fmaxf(v2, v3));
      float s = __expf(v0 - m) + __expf(v1 - m) + __expf(v2 - m) + __expf(v3 - m);
      int R = wm + mi * 16 + q * 4 + r;
      rbuf[R * 33 + (w & 1) * 16 + c16] = make_float2(m, s);
    }
  __syncthreads();
  if (t < 128) {
    float M = rbuf[t * 33].x;
    #pragma unroll
    for (int x = 1; x < 32; ++x) M = fmaxf(M, rbuf[t * 33 + x].x);
    float S = 0.f;
    #pragma unroll
    for (int x = 0; x < 32; ++x) { float2 p = rbuf[t * 33 + x]; S += p.y * __expf(p.x - M); }
    row_pmax[bn * B_DIM + bm * 128 + t] = M;   // chunk-major: coalesced here AND in combine
    row_psum[bn * B_DIM + bm * 128 + t] = S;
  }
  __syncthreads();
  // ---- cols phase 1: per-lane reduce over 16 (mi,r) values, scatter to cbuf[128][9] ----
  float2* cbuf = (float2*)smem;
  #pragma unroll
  for (int ni = 0; ni < 4; ++ni) {
    float m = -3.0e38f;
    #pragma unroll
    for (int mi = 0; mi < 4; ++mi)
      #pragma unroll
      for (int r = 0; r < 4; ++r) m = fmaxf(m, acc[mi][ni][r]);
    float s = 0.f;
    #pragma unroll
    for (int mi = 0; mi < 4; ++mi)
      #pragma unroll
      for (int r = 0; r < 4; ++r) s += __expf(acc[mi][ni][r] - m);
    int C = wn + ni * 16 + c16;
    cbuf[C * 9 + (w >> 1) * 4 + q] = make_float2(m, s);
  }
  __syncthreads();
  if (t < 128) {
    float M = cbuf[t * 9].x;
    #pragma unroll
    for (int y = 1; y < 8; ++y) M = fmaxf(M, cbuf[t * 9 + y].x);
    float S = 0.f;
    #pragma unroll
    for (int y = 0; y < 8; ++y) { float2 p = cbuf[t * 9 + y]; S += p.y * __expf(p.x - M); }
    col_pmax[bm * B_DIM + bn * 128 + t] = M;
    col_psum[bm * B_DIM + bn * 128 + t] = S;
  }
}

// ---------------- combine: thread per item; last block (counter) writes d_out ----------------
__global__ __launch_bounds__(256) void combine_kernel(
    const float* __restrict__ row_pmax, const float* __restrict__ row_psum,
    const float* __restrict__ col_pmax, const float* __restrict__ col_psum,
    const float* __restrict__ diagp, const float* __restrict__ log_tau,
    float* __restrict__ acc, unsigned* __restrict__ counter,
    float* __restrict__ out) {
  const int t = threadIdx.x;
  const int item = blockIdx.x * 256 + t;       // 0..4095 rows, 4096..8191 cols
  const float* pm; const float* ps; int i;
  if (item < B_DIM) { pm = row_pmax; ps = row_psum; i = item; }
  else              { pm = col_pmax; ps = col_psum; i = item - B_DIM; }
  float M = pm[i];
  #pragma unroll
  for (int k = 1; k < NCHUNK; ++k) M = fmaxf(M, pm[k * B_DIM + i]);
  float S = 0.f;
  #pragma unroll
  for (int k = 0; k < NCHUNK; ++k) S += ps[k * B_DIM + i] * __expf(pm[k * B_DIM + i] - M);
  float local = M + __logf(S);
  if (blockIdx.x == 0) {                       // fold diag partials (512) into block 0
    float tau = fminf(__expf(log_tau[0]), 100.0f);
    local += -2.0f * tau * (diagp[t] + diagp[t + 256]);
  }
  #pragma unroll
  for (int off = 1; off < 64; off <<= 1) local += __shfl_xor(local, off);
  __shared__ float red[4];
  int w = t >> 6, lane = t & 63;
  if (lane == 0) red[w] = local;
  __syncthreads();
  if (t == 0) {
    atomicAdd(acc, red[0] + red[1] + red[2] + red[3]);
    __threadfence();
    unsigned old = atomicAdd(counter, 1u);
    if (old == 31u) {                          // last of the 32 blocks: finalize
      float v = atomicAdd(acc, 0.0f);          // coherent read after all adds
      out[0] = v * (1.0f / 8192.0f);
    }
  }
}

// ---------------- launch ----------------
extern "C" void kernel_launch(void* const* d_in, const int* in_sizes, int n_in,
                              void* d_out, int out_size, void* d_ws, size_t ws_size,
                              hipStream_t stream) {
  const float* ftir    = (const float*)d_in[0];
  const float* raman   = (const float*)d_in[1];
  // d_in[2] = labels (int64) — unused by the reference output
  const float* log_tau = (const float*)d_in[3];
  float* out = (float*)d_out;

  char* ws = (char*)d_ws;
  // ws layout: Abf 4MiB | Bbf 4MiB | row_pmax 512K | row_psum 512K |
  //            col_pmax 512K | col_psum 512K | diagp 2K | flags: acc,cnt,qcnt[8],pcnt[32]
  __bf16* Abf     = (__bf16*)(ws);
  __bf16* Bbf     = (__bf16*)(ws + (4u << 20));
  float* row_pmax = (float*)(ws + (8u << 20));
  float* row_psum = (float*)(ws + (8u << 20) + (512u << 10));
  float* col_pmax = (float*)(ws + (9u << 20));
  float* col_psum = (float*)(ws + (9u << 20) + (512u << 10));
  float* diagp    = (float*)(ws + (10u << 20));
  char*  flags    = ws + (10u << 20) + 4096;
  float*    acc   = (float*)(flags);
  unsigned* cnt   = (unsigned*)(flags + 4);
  unsigned* qcnt  = (unsigned*)(flags + 8);
  unsigned* pcnt  = (unsigned*)(flags + 8 + 32);

  hipMemsetAsync(flags, 0, 8 + 32 + 128, stream);
  fused_kernel<<<1024, 256, 0, stream>>>(ftir, raman, log_tau, Abf, Bbf, diagp,
                                         qcnt, pcnt,
                                         row_pmax, row_psum, col_pmax, col_psum);
  combine_kernel<<<32, 256, 0, stream>>>(row_pmax, row_psum, col_pmax, col_psum,
                                         diagp, log_tau, acc, cnt, out);
}

// Round 12
// 143.428 us; speedup vs baseline: 1.6618x; 1.6618x over previous
//
#include <hip/hip_runtime.h>
#include <hip/hip_bf16.h>
#include <stdint.h>

// ConstrastiveLoss2: loss = (sum_i lse_row(i) + sum_j lse_col(j) - 2*tau*sum_e a[e]b[e]) / (2B)
// logits = tau * ftir @ raman^T, tau = min(exp(log_tau), 100), B=4096, D=512.
// R12: R9 (best, 96.8us) + combine fused into the gemm via last-arriver panel
// counters (no spinning): 32nd block per row/col panel combines that panel's
// partials in-place, 64th finisher writes d_out. 2 dispatches total.

typedef float f32x4 __attribute__((ext_vector_type(4)));
typedef __bf16 bf16x8 __attribute__((ext_vector_type(8)));
typedef __bf16 bf16x4 __attribute__((ext_vector_type(4)));

#define B_DIM 4096
#define D_DIM 512

__device__ __forceinline__ void gld_lds16(const void* g, void* l) {
  __builtin_amdgcn_global_load_lds(
      (const __attribute__((address_space(1))) unsigned int*)g,
      (__attribute__((address_space(3))) unsigned int*)l,
      16, 0, 0);
}

// ---------------- cast fp32 -> bf16 (4-block XOR swizzle) + fused diag partials ----------------
// Within each row's aligned 64B group (4 x 16B blocks), logical block g is
// stored at physical position g ^ ((row>>1)&3). Block 0 zeroes the 66 flag
// words (acc, finish, rowdone[32], coldone[32]) — ws is poisoned 0xAA.
__global__ __launch_bounds__(256) void cast_diag_kernel(
    const float* __restrict__ A, const float* __restrict__ Bm,
    __bf16* __restrict__ Abf, __bf16* __restrict__ Bbf,
    float* __restrict__ diagp, unsigned* __restrict__ flags) {
  if (blockIdx.x == 0 && threadIdx.x < 66) flags[threadIdx.x] = 0u;
  const float4* A4 = (const float4*)A;
  const float4* B4 = (const float4*)Bm;
  bf16x4* Ab4 = (bf16x4*)Abf;
  bf16x4* Bb4 = (bf16x4*)Bbf;
  int idx = blockIdx.x * 256 + threadIdx.x;
  float local = 0.f;
  #pragma unroll
  for (int it = 0; it < 4; ++it, idx += 512 * 256) {
    int row = idx >> 7, el4 = idx & 127;      // el4: [2:1]=16B-block g, [0]=8B half
    int g = (el4 >> 1) & 3;
    int gswz = g ^ ((row >> 1) & 3);
    int el4p = (el4 & ~6) | (gswz << 1);
    int pidx = row * 128 + el4p;
    float4 va = A4[idx], vb = B4[idx];
    bf16x4 oa, ob;
    oa[0]=(__bf16)va.x; oa[1]=(__bf16)va.y; oa[2]=(__bf16)va.z; oa[3]=(__bf16)va.w;
    ob[0]=(__bf16)vb.x; ob[1]=(__bf16)vb.y; ob[2]=(__bf16)vb.z; ob[3]=(__bf16)vb.w;
    Ab4[pidx] = oa; Bb4[pidx] = ob;
    local += va.x*vb.x + va.y*vb.y + va.z*vb.z + va.w*vb.w;
  }
  #pragma unroll
  for (int off = 1; off < 64; off <<= 1) local += __shfl_xor(local, off);
  __shared__ float red[4];
  int w = threadIdx.x >> 6, lane = threadIdx.x & 63;
  if (lane == 0) red[w] = local;
  __syncthreads();
  if (threadIdx.x == 0)
    diagp[blockIdx.x] = red[0] + red[1] + red[2] + red[3];
}

// ---------------- fused GEMM + lse partials + last-arriver combine ----------------
// 1024 blocks (XCD-swizzled); 4 waves in 2x2; wave computes 64x64 via 4x4 of
// 16x16x32 MFMA. BK=32, 3-stage vmcnt-pipelined async DMA (R9-identical).
__global__ __launch_bounds__(256, 3) void gemm_lse_kernel(
    const __bf16* __restrict__ A, const __bf16* __restrict__ Bm,
    const float* __restrict__ log_tau, const float* __restrict__ diagp,
    float* __restrict__ row_pmax, float* __restrict__ row_psum,
    float* __restrict__ col_pmax, float* __restrict__ col_psum,
    unsigned* __restrict__ flags, float* __restrict__ out) {
  __shared__ char smem[49152];                 // 3 stages x (A 8KB + B 8KB); epilogue overlay
  __shared__ unsigned sflag;
  __shared__ float red2[4];
  float* acc            = (float*)flags;       // [0]
  unsigned* finish      = flags + 1;           // [1]
  unsigned* rowdone     = flags + 2;           // [2..33]
  unsigned* coldone     = flags + 34;          // [34..65]
  // XCD swizzle: blk%8 ~ XCD id; each XCD gets an 8(bm) x 16(bn) cluster.
  const int blk = blockIdx.x;
  const int xcd = blk & 7, loc = blk >> 3;
  const int bm = (xcd & 3) * 8 + (loc & 7);
  const int bn = (xcd >> 2) * 16 + (loc >> 3);
  const int t = threadIdx.x;
  const int lane = t & 63;
  const int w = t >> 6;
  const int wm = (w >> 1) * 64, wn = (w & 1) * 64;
  const int q = lane >> 4, c16 = lane & 15;
  const int kbs = q ^ ((c16 >> 1) & 3);        // physical 16B-block for this lane

  f32x4 acc_r[4][4] = {};

  const char* Ag = (const char*)A + (size_t)(bm * 128 + (t >> 2)) * 1024 + (t & 3) * 16;
  const char* Bg = (const char*)Bm + (size_t)(bn * 128 + (t >> 2)) * 1024 + (t & 3) * 16;

  #define ISSUE_STAGE(kt, p)                                                  \
    do {                                                                      \
      const char* ag = Ag + (kt) * 64;                                        \
      const char* bg = Bg + (kt) * 64;                                        \
      char* Al = smem + (p) * 16384 + t * 16;                                 \
      char* Bl = smem + (p) * 16384 + 8192 + t * 16;                          \
      _Pragma("unroll")                                                       \
      for (int i = 0; i < 2; ++i) {                                           \
        gld_lds16(ag + i * 65536, Al + i * 4096);                             \
        gld_lds16(bg + i * 65536, Bl + i * 4096);                             \
      }                                                                       \
    } while (0)

  #define COMPUTE(p)                                                          \
    do {                                                                      \
      const char* Ab = smem + (p) * 16384;                                    \
      const char* Bb = Ab + 8192;                                             \
      bf16x8 af[4], bfr[4];                                                   \
      _Pragma("unroll")                                                       \
      for (int mi = 0; mi < 4; ++mi)                                          \
        af[mi] = *(const bf16x8*)(Ab + (wm + mi * 16 + c16) * 64 + kbs * 16); \
      _Pragma("unroll")                                                       \
      for (int ni = 0; ni < 4; ++ni)                                          \
        bfr[ni] = *(const bf16x8*)(Bb + (wn + ni * 16 + c16) * 64 + kbs * 16);\
      _Pragma("unroll")                                                       \
      for (int mi = 0; mi < 4; ++mi)                                          \
        _Pragma("unroll")                                                     \
        for (int ni = 0; ni < 4; ++ni)                                        \
          acc_r[mi][ni] = __builtin_amdgcn_mfma_f32_16x16x32_bf16(            \
              af[mi], bfr[ni], acc_r[mi][ni], 0, 0, 0);                       \
    } while (0)

  ISSUE_STAGE(0, 0);
  ISSUE_STAGE(1, 1);
  for (int kt = 0; kt < 15; ++kt) {
    asm volatile("s_waitcnt vmcnt(4)" ::: "memory");  // stage kt landed; kt+1 in flight
    __builtin_amdgcn_s_barrier();              // raw: no full drain
    asm volatile("" ::: "memory");
    if (kt < 14) ISSUE_STAGE(kt + 2, (kt + 2) % 3);   // buf (kt-1)%3: readers done
    COMPUTE(kt % 3);
  }
  asm volatile("s_waitcnt vmcnt(0)" ::: "memory");
  __builtin_amdgcn_s_barrier();
  asm volatile("" ::: "memory");
  COMPUTE(15 % 3);
  __syncthreads();                             // all reads done before epilogue overlay
  #undef ISSUE_STAGE
  #undef COMPUTE

  const float tau = fminf(__expf(log_tau[0]), 100.0f);
  #pragma unroll
  for (int mi = 0; mi < 4; ++mi)
    #pragma unroll
    for (int ni = 0; ni < 4; ++ni)
      acc_r[mi][ni] *= tau;

  // C layout (m89): col = wn + ni*16 + c16, row = wm + mi*16 + q*4 + r.
  // ---- rows phase 1: per-lane reduce over 4 ni values, scatter to rowbuf[128][33] ----
  float2* rbuf = (float2*)smem;
  #pragma unroll
  for (int mi = 0; mi < 4; ++mi)
    #pragma unroll
    for (int r = 0; r < 4; ++r) {
      float v0 = acc_r[mi][0][r], v1 = acc_r[mi][1][r], v2 = acc_r[mi][2][r], v3 = acc_r[mi][3][r];
      float m = fmaxf(fmaxf(v0, v1), fmaxf(v2, v3));
      float s = __expf(v0 - m) + __expf(v1 - m) + __expf(v2 - m) + __expf(v3 - m);
      int R = wm + mi * 16 + q * 4 + r;
      rbuf[R * 33 + (w & 1) * 16 + c16] = make_float2(m, s);
    }
  __syncthreads();
  if (t < 128) {
    float M = rbuf[t * 33].x;
    #pragma unroll
    for (int x = 1; x < 32; ++x) M = fmaxf(M, rbuf[t * 33 + x].x);
    float S = 0.f;
    #pragma unroll
    for (int x = 0; x < 32; ++x) { float2 p = rbuf[t * 33 + x]; S += p.y * __expf(p.x - M); }
    row_pmax[bn * B_DIM + bm * 128 + t] = M;   // chunk-major
    row_psum[bn * B_DIM + bm * 128 + t] = S;
  }
  __syncthreads();
  // ---- cols phase 1: per-lane reduce over 16 (mi,r) values, scatter to cbuf[128][9] ----
  float2* cbuf = (float2*)smem;
  #pragma unroll
  for (int ni = 0; ni < 4; ++ni) {
    float m = -3.0e38f;
    #pragma unroll
    for (int mi = 0; mi < 4; ++mi)
      #pragma unroll
      for (int r = 0; r < 4; ++r) m = fmaxf(m, acc_r[mi][ni][r]);
    float s = 0.f;
    #pragma unroll
    for (int mi = 0; mi < 4; ++mi)
      #pragma unroll
      for (int r = 0; r < 4; ++r) s += __expf(acc_r[mi][ni][r] - m);
    int C = wn + ni * 16 + c16;
    cbuf[C * 9 + (w >> 1) * 4 + q] = make_float2(m, s);
  }
  __syncthreads();
  if (t < 128) {
    float M = cbuf[t * 9].x;
    #pragma unroll
    for (int y = 1; y < 8; ++y) M = fmaxf(M, cbuf[t * 9 + y].x);
    float S = 0.f;
    #pragma unroll
    for (int y = 0; y < 8; ++y) { float2 p = cbuf[t * 9 + y]; S += p.y * __expf(p.x - M); }
    col_pmax[bm * B_DIM + bn * 128 + t] = M;
    col_psum[bm * B_DIM + bn * 128 + t] = S;
  }

  // ================= last-arriver combine (no waiting) =================
  __syncthreads();                             // all partial stores drained to L2
  if (t == 0) {
    __threadfence();                           // release: writeback XCD L2
    unsigned r1 = atomicAdd(&rowdone[bm], 1u); // 32 increments per panel
    unsigned r2 = atomicAdd(&coldone[bn], 1u);
    sflag = (r1 == 31u ? 1u : 0u) | (r2 == 31u ? 2u : 0u);
  }
  __syncthreads();
  const unsigned f = sflag;                    // block-uniform
  if (f != 0u) {
    __threadfence();                           // acquire: invalidate stale lines
    float tot = 0.f;
    if (f & 1u) {                              // row combine for panel bm (+ diag slice)
      float local = 0.f;
      if (t < 128) {
        const int item = bm * 128 + t;
        float M = row_pmax[item];
        #pragma unroll
        for (int k = 1; k < 32; ++k) M = fmaxf(M, row_pmax[k * B_DIM + item]);
        float S = 0.f;
        #pragma unroll
        for (int k = 0; k < 32; ++k)
          S += row_psum[k * B_DIM + item] * __expf(row_pmax[k * B_DIM + item] - M);
        local = M + __logf(S);
      } else if (t < 144) {
        local = -2.0f * tau * diagp[bm * 16 + (t - 128)];
      }
      #pragma unroll
      for (int off = 1; off < 64; off <<= 1) local += __shfl_xor(local, off);
      if (lane == 0) red2[w] = local;
      __syncthreads();
      if (t == 0) tot += red2[0] + red2[1] + red2[2] + red2[3];
      __syncthreads();
    }
    if (f & 2u) {                              // col combine for panel bn
      float local = 0.f;
      if (t < 128) {
        const int item = bn * 128 + t;
        float M = col_pmax[item];
        #pragma unroll
        for (int k = 1; k < 32; ++k) M = fmaxf(M, col_pmax[k * B_DIM + item]);
        float S = 0.f;
        #pragma unroll
        for (int k = 0; k < 32; ++k)
          S += col_psum[k * B_DIM + item] * __expf(col_pmax[k * B_DIM + item] - M);
        local = M + __logf(S);
      }
      #pragma unroll
      for (int off = 1; off < 64; off <<= 1) local += __shfl_xor(local, off);
      if (lane == 0) red2[w] = local;
      __syncthreads();
      if (t == 0) tot += red2[0] + red2[1] + red2[2] + red2[3];
    }
    if (t == 0) {
      atomicAdd(acc, tot);
      __threadfence();
      const unsigned n = (f == 3u) ? 2u : 1u;
      unsigned old = atomicAdd(finish, n);     // 64 total increments
      if (old + n == 64u) {                    // exactly one finalizer
        float v = atomicAdd(acc, 0.0f);        // coherent read after all adds
        out[0] = v * (1.0f / 8192.0f);
      }
    }
  }
}

// ---------------- launch ----------------
extern "C" void kernel_launch(void* const* d_in, const int* in_sizes, int n_in,
                              void* d_out, int out_size, void* d_ws, size_t ws_size,
                              hipStream_t stream) {
  const float* ftir    = (const float*)d_in[0];
  const float* raman   = (const float*)d_in[1];
  // d_in[2] = labels (int64) — unused by the reference output
  const float* log_tau = (const float*)d_in[3];
  float* out = (float*)d_out;

  char* ws = (char*)d_ws;
  // ws layout: Abf 4MiB | Bbf 4MiB | row_pmax 512K | row_psum 512K |
  //            col_pmax 512K | col_psum 512K | diagp 2K | flags[66]
  __bf16* Abf     = (__bf16*)(ws);
  __bf16* Bbf     = (__bf16*)(ws + (4u << 20));
  float* row_pmax = (float*)(ws + (8u << 20));
  float* row_psum = (float*)(ws + (8u << 20) + (512u << 10));
  float* col_pmax = (float*)(ws + (9u << 20));
  float* col_psum = (float*)(ws + (9u << 20) + (512u << 10));
  float* diagp    = (float*)(ws + (10u << 20));
  unsigned* flags = (unsigned*)(ws + (10u << 20) + 4096);

  cast_diag_kernel<<<512, 256, 0, stream>>>(ftir, raman, Abf, Bbf, diagp, flags);
  gemm_lse_kernel<<<1024, 256, 0, stream>>>(Abf, Bbf, log_tau, diagp,
                                            row_pmax, row_psum, col_pmax, col_psum,
                                            flags, out);
}

// Round 13
// 98.678 us; speedup vs baseline: 2.4153x; 1.4535x over previous
//
#include <hip/hip_runtime.h>
#include <hip/hip_bf16.h>
#include <stdint.h>

// ConstrastiveLoss2: loss = (sum_i lse_row(i) + sum_j lse_col(j) - 2*tau*sum_e a[e]b[e]) / (2B)
// logits = tau * ftir @ raman^T, tau = min(exp(log_tau), 100), B=4096, D=512.
// R13 = R9 verbatim (best known: 96.8us). 3-stage BK=32 vmcnt-pipelined gemm,
// XOR-swizzled bf16 panels, shuffle-free epilogue, 3 dispatches.
// Rejected by experiment: VGPR prefetch (R5 spill), fp32 in-gemm staging (R10),
// producer/consumer fusion (R11), last-arriver combine fusion (R12).

typedef float f32x4 __attribute__((ext_vector_type(4)));
typedef __bf16 bf16x8 __attribute__((ext_vector_type(8)));
typedef __bf16 bf16x4 __attribute__((ext_vector_type(4)));

#define B_DIM 4096
#define D_DIM 512
#define NCHUNK 32   // partial chunks per row/col (one per 128-tile in the other dim)

__device__ __forceinline__ void gld_lds16(const void* g, void* l) {
  __builtin_amdgcn_global_load_lds(
      (const __attribute__((address_space(1))) unsigned int*)g,
      (__attribute__((address_space(3))) unsigned int*)l,
      16, 0, 0);
}

// ---------------- cast fp32 -> bf16 (4-block XOR swizzle) + fused diag partials ----------------
// Within each row's aligned 64B group (4 x 16B blocks), logical block g is
// stored at physical position g ^ ((row>>1)&3). Also zeroes acc + counter.
__global__ __launch_bounds__(256) void cast_diag_kernel(
    const float* __restrict__ A, const float* __restrict__ Bm,
    __bf16* __restrict__ Abf, __bf16* __restrict__ Bbf,
    float* __restrict__ diagp, float* __restrict__ acc,
    unsigned* __restrict__ counter) {
  if (blockIdx.x == 0 && threadIdx.x == 0) { acc[0] = 0.f; counter[0] = 0u; }
  const float4* A4 = (const float4*)A;
  const float4* B4 = (const float4*)Bm;
  bf16x4* Ab4 = (bf16x4*)Abf;
  bf16x4* Bb4 = (bf16x4*)Bbf;
  int idx = blockIdx.x * 256 + threadIdx.x;
  float local = 0.f;
  #pragma unroll
  for (int it = 0; it < 4; ++it, idx += 512 * 256) {
    int row = idx >> 7, el4 = idx & 127;      // el4: [2:1]=16B-block g, [0]=8B half
    int g = (el4 >> 1) & 3;
    int gswz = g ^ ((row >> 1) & 3);
    int el4p = (el4 & ~6) | (gswz << 1);
    int pidx = row * 128 + el4p;
    float4 va = A4[idx], vb = B4[idx];
    bf16x4 oa, ob;
    oa[0]=(__bf16)va.x; oa[1]=(__bf16)va.y; oa[2]=(__bf16)va.z; oa[3]=(__bf16)va.w;
    ob[0]=(__bf16)vb.x; ob[1]=(__bf16)vb.y; ob[2]=(__bf16)vb.z; ob[3]=(__bf16)vb.w;
    Ab4[pidx] = oa; Bb4[pidx] = ob;
    local += va.x*vb.x + va.y*vb.y + va.z*vb.z + va.w*vb.w;
  }
  #pragma unroll
  for (int off = 1; off < 64; off <<= 1) local += __shfl_xor(local, off);
  __shared__ float red[4];
  int w = threadIdx.x >> 6, lane = threadIdx.x & 63;
  if (lane == 0) red[w] = local;
  __syncthreads();
  if (threadIdx.x == 0)
    diagp[blockIdx.x] = red[0] + red[1] + red[2] + red[3];
}

// ---------------- fused GEMM + per-tile row/col (max, sumexp) partials ----------------
// 1024 blocks (XCD-swizzled); 4 waves in 2x2; wave computes 64x64 via 4x4 of
// 16x16x32 MFMA. BK=32, 3-stage pipelined async DMA; 3 blocks/CU.
__global__ __launch_bounds__(256, 3) void gemm_lse_kernel(
    const __bf16* __restrict__ A, const __bf16* __restrict__ Bm,
    const float* __restrict__ log_tau,
    float* __restrict__ row_pmax, float* __restrict__ row_psum,
    float* __restrict__ col_pmax, float* __restrict__ col_psum) {
  __shared__ char smem[49152];                 // 3 stages x (A 8KB + B 8KB); epilogue overlay
  // XCD swizzle: blk%8 ~ XCD id; each XCD gets an 8(bm) x 16(bn) cluster.
  const int blk = blockIdx.x;
  const int xcd = blk & 7, loc = blk >> 3;
  const int bm = (xcd & 3) * 8 + (loc & 7);
  const int bn = (xcd >> 2) * 16 + (loc >> 3);
  const int t = threadIdx.x;
  const int lane = t & 63;
  const int w = t >> 6;
  const int wm = (w >> 1) * 64, wn = (w & 1) * 64;
  const int q = lane >> 4, c16 = lane & 15;
  const int kbs = q ^ ((c16 >> 1) & 3);        // physical 16B-block for this lane

  f32x4 acc[4][4] = {};

  // staging: thread t -> row (t>>2)+64*i, 16B-block t&3 of the stage's 64B row-group
  const char* Ag = (const char*)A + (size_t)(bm * 128 + (t >> 2)) * 1024 + (t & 3) * 16;
  const char* Bg = (const char*)Bm + (size_t)(bn * 128 + (t >> 2)) * 1024 + (t & 3) * 16;

  // issue one BK=32 stage's DMA into buffer p (linear, lane-contiguous; 4 instr)
  #define ISSUE_STAGE(kt, p)                                                  \
    do {                                                                      \
      const char* ag = Ag + (kt) * 64;                                        \
      const char* bg = Bg + (kt) * 64;                                        \
      char* Al = smem + (p) * 16384 + t * 16;                                 \
      char* Bl = smem + (p) * 16384 + 8192 + t * 16;                          \
      _Pragma("unroll")                                                       \
      for (int i = 0; i < 2; ++i) {                                           \
        gld_lds16(ag + i * 65536, Al + i * 4096);                             \
        gld_lds16(bg + i * 65536, Bl + i * 4096);                             \
      }                                                                       \
    } while (0)

  #define COMPUTE(p)                                                          \
    do {                                                                      \
      const char* Ab = smem + (p) * 16384;                                    \
      const char* Bb = Ab + 8192;                                             \
      bf16x8 af[4], bfr[4];                                                   \
      _Pragma("unroll")                                                       \
      for (int mi = 0; mi < 4; ++mi)                                          \
        af[mi] = *(const bf16x8*)(Ab + (wm + mi * 16 + c16) * 64 + kbs * 16); \
      _Pragma("unroll")                                                       \
      for (int ni = 0; ni < 4; ++ni)                                          \
        bfr[ni] = *(const bf16x8*)(Bb + (wn + ni * 16 + c16) * 64 + kbs * 16);\
      _Pragma("unroll")                                                       \
      for (int mi = 0; mi < 4; ++mi)                                          \
        _Pragma("unroll")                                                     \
        for (int ni = 0; ni < 4; ++ni)                                        \
          acc[mi][ni] = __builtin_amdgcn_mfma_f32_16x16x32_bf16(              \
              af[mi], bfr[ni], acc[mi][ni], 0, 0, 0);                         \
    } while (0)

  ISSUE_STAGE(0, 0);
  ISSUE_STAGE(1, 1);
  for (int kt = 0; kt < 15; ++kt) {
    // stage kt landed when <=4 VMEM remain (stage kt+1 stays in flight)
    asm volatile("s_waitcnt vmcnt(4)" ::: "memory");
    __builtin_amdgcn_s_barrier();              // raw: no vmcnt(0) drain
    asm volatile("" ::: "memory");             // keep ds_reads below the barrier
    if (kt < 14) ISSUE_STAGE(kt + 2, (kt + 2) % 3);  // overwrites buf (kt-1)%3: readers done
    COMPUTE(kt % 3);
  }
  asm volatile("s_waitcnt vmcnt(0)" ::: "memory");   // last stage (15) fully landed
  __builtin_amdgcn_s_barrier();
  asm volatile("" ::: "memory");
  COMPUTE(15 % 3);
  __syncthreads();                             // full drain before epilogue smem overlay
  #undef ISSUE_STAGE
  #undef COMPUTE

  const float tau = fminf(__expf(log_tau[0]), 100.0f);
  #pragma unroll
  for (int mi = 0; mi < 4; ++mi)
    #pragma unroll
    for (int ni = 0; ni < 4; ++ni)
      acc[mi][ni] *= tau;

  // C layout (m89): col = wn + ni*16 + c16, row = wm + mi*16 + q*4 + r.
  // ---- rows phase 1: per-lane reduce over 4 ni values, scatter to rowbuf[128][33] ----
  float2* rbuf = (float2*)smem;
  #pragma unroll
  for (int mi = 0; mi < 4; ++mi)
    #pragma unroll
    for (int r = 0; r < 4; ++r) {
      float v0 = acc[mi][0][r], v1 = acc[mi][1][r], v2 = acc[mi][2][r], v3 = acc[mi][3][r];
      float m = fmaxf(fmaxf(v0, v1), fmaxf(v2, v3));
      float s = __expf(v0 - m) + __expf(v1 - m) + __expf(v2 - m) + __expf(v3 - m);
      int R = wm + mi * 16 + q * 4 + r;
      rbuf[R * 33 + (w & 1) * 16 + c16] = make_float2(m, s);
    }
  __syncthreads();
  // ---- rows phase 2: thread t<128 combines row t's 32 partials ----
  if (t < 128) {
    float M = rbuf[t * 33].x;
    #pragma unroll
    for (int x = 1; x < 32; ++x) M = fmaxf(M, rbuf[t * 33 + x].x);
    float S = 0.f;
    #pragma unroll
    for (int x = 0; x < 32; ++x) { float2 p = rbuf[t * 33 + x]; S += p.y * __expf(p.x - M); }
    row_pmax[bn * B_DIM + bm * 128 + t] = M;   // chunk-major: coalesced here AND in combine
    row_psum[bn * B_DIM + bm * 128 + t] = S;
  }
  __syncthreads();
  // ---- cols phase 1: per-lane reduce over 16 (mi,r) values, scatter to cbuf[128][9] ----
  float2* cbuf = (float2*)smem;
  #pragma unroll
  for (int ni = 0; ni < 4; ++ni) {
    float m = -3.0e38f;
    #pragma unroll
    for (int mi = 0; mi < 4; ++mi)
      #pragma unroll
      for (int r = 0; r < 4; ++r) m = fmaxf(m, acc[mi][ni][r]);
    float s = 0.f;
    #pragma unroll
    for (int mi = 0; mi < 4; ++mi)
      #pragma unroll
      for (int r = 0; r < 4; ++r) s += __expf(acc[mi][ni][r] - m);
    int C = wn + ni * 16 + c16;
    cbuf[C * 9 + (w >> 1) * 4 + q] = make_float2(m, s);
  }
  __syncthreads();
  // ---- cols phase 2: thread t<128 combines col t's 8 partials ----
  if (t < 128) {
    float M = cbuf[t * 9].x;
    #pragma unroll
    for (int y = 1; y < 8; ++y) M = fmaxf(M, cbuf[t * 9 + y].x);
    float S = 0.f;
    #pragma unroll
    for (int y = 0; y < 8; ++y) { float2 p = cbuf[t * 9 + y]; S += p.y * __expf(p.x - M); }
    col_pmax[bm * B_DIM + bn * 128 + t] = M;
    col_psum[bm * B_DIM + bn * 128 + t] = S;
  }
}

// ---------------- combine: thread per item; last block (counter) writes d_out ----------------
__global__ __launch_bounds__(256) void combine_kernel(
    const float* __restrict__ row_pmax, const float* __restrict__ row_psum,
    const float* __restrict__ col_pmax, const float* __restrict__ col_psum,
    const float* __restrict__ diagp, const float* __restrict__ log_tau,
    float* __restrict__ acc, unsigned* __restrict__ counter,
    float* __restrict__ out) {
  const int t = threadIdx.x;
  const int item = blockIdx.x * 256 + t;       // 0..4095 rows, 4096..8191 cols
  const float* pm; const float* ps; int i;
  if (item < B_DIM) { pm = row_pmax; ps = row_psum; i = item; }
  else              { pm = col_pmax; ps = col_psum; i = item - B_DIM; }
  float M = pm[i];
  #pragma unroll
  for (int k = 1; k < NCHUNK; ++k) M = fmaxf(M, pm[k * B_DIM + i]);
  float S = 0.f;
  #pragma unroll
  for (int k = 0; k < NCHUNK; ++k) S += ps[k * B_DIM + i] * __expf(pm[k * B_DIM + i] - M);
  float local = M + __logf(S);
  if (blockIdx.x == 0) {                       // fold diag partials (512) into block 0
    float tau = fminf(__expf(log_tau[0]), 100.0f);
    local += -2.0f * tau * (diagp[t] + diagp[t + 256]);
  }
  #pragma unroll
  for (int off = 1; off < 64; off <<= 1) local += __shfl_xor(local, off);
  __shared__ float red[4];
  int w = t >> 6, lane = t & 63;
  if (lane == 0) red[w] = local;
  __syncthreads();
  if (t == 0) {
    atomicAdd(acc, red[0] + red[1] + red[2] + red[3]);
    __threadfence();
    unsigned old = atomicAdd(counter, 1u);
    if (old == 31u) {                          // last of the 32 blocks: finalize
      float v = atomicAdd(acc, 0.0f);          // coherent read after all adds
      out[0] = v * (1.0f / 8192.0f);
    }
  }
}

// ---------------- launch ----------------
extern "C" void kernel_launch(void* const* d_in, const int* in_sizes, int n_in,
                              void* d_out, int out_size, void* d_ws, size_t ws_size,
                              hipStream_t stream) {
  const float* ftir    = (const float*)d_in[0];
  const float* raman   = (const float*)d_in[1];
  // d_in[2] = labels (int64) — unused by the reference output
  const float* log_tau = (const float*)d_in[3];
  float* out = (float*)d_out;

  char* ws = (char*)d_ws;
  // ws layout: Abf 4MiB | Bbf 4MiB | row_pmax 512K | row_psum 512K |
  //            col_pmax 512K | col_psum 512K | diagp 2K | acc 4B | counter 4B
  __bf16* Abf     = (__bf16*)(ws);
  __bf16* Bbf     = (__bf16*)(ws + (4u << 20));
  float* row_pmax = (float*)(ws + (8u << 20));
  float* row_psum = (float*)(ws + (8u << 20) + (512u << 10));
  float* col_pmax = (float*)(ws + (9u << 20));
  float* col_psum = (float*)(ws + (9u << 20) + (512u << 10));
  float* diagp    = (float*)(ws + (10u << 20));
  float* acc      = (float*)(ws + (10u << 20) + 4096);
  unsigned* cnt   = (unsigned*)(ws + (10u << 20) + 4096 + 4);

  cast_diag_kernel<<<512, 256, 0, stream>>>(ftir, raman, Abf, Bbf, diagp, acc, cnt);
  gemm_lse_kernel<<<1024, 256, 0, stream>>>(Abf, Bbf, log_tau,
                                            row_pmax, row_psum, col_pmax, col_psum);
  combine_kernel<<<32, 256, 0, stream>>>(row_pmax, row_psum, col_pmax, col_psum,
                                         diagp, log_tau, acc, cnt, out);
}